// Round 4
// baseline (1057.735 us; speedup 1.0000x reference)
//
#include <hip/hip_runtime.h>
#include <stdint.h>

// Problem constants: B=4, S=2048, D=1024, E=8, F=4096, k=2 — FP32 I/O, bf16 MFMA compute
#define T_TOK   8192
#define DMODEL  1024
#define NEXP    8
#define FFN     4096
#define TASSIGN 16384   // T_TOK * k

typedef unsigned short u16;
typedef __attribute__((ext_vector_type(8))) short short8;   // MFMA bf16 A/B frag
typedef __attribute__((ext_vector_type(8))) u16 u16x8;
typedef __attribute__((ext_vector_type(4))) u16 u16x4;
typedef __attribute__((ext_vector_type(4))) float f32x4;    // MFMA C/D frag

__device__ __forceinline__ float bf2f(u16 u) {
  union { unsigned int i; float f; } v; v.i = ((unsigned int)u) << 16; return v.f;
}
__device__ __forceinline__ u16 f2bf(float f) {
  union { float f; unsigned int i; } v; v.f = f;
  unsigned int x = v.i;
  x += 0x7fffu + ((x >> 16) & 1u);   // round-to-nearest-even
  return (u16)(x >> 16);
}
// jax.nn.gelu default: approximate=True (tanh form)
__device__ __forceinline__ float gelu_tanh(float x) {
  float z = 0.7978845608028654f * x * (1.0f + 0.044715f * x * x);
  float t = 1.0f - 2.0f / (__expf(2.0f * z) + 1.0f);
  return 0.5f * x * (1.0f + t);
}
// async global->LDS, 16B per lane; LDS dest is wave-uniform base + lane*16
__device__ __forceinline__ void async16(const void* g, void* l) {
  __builtin_amdgcn_global_load_lds((__attribute__((address_space(1))) void*)g,
                                   (__attribute__((address_space(3))) void*)l,
                                   16, 0, 0);
}

// ---------------------------------------------------------------- meta init --
__global__ void init_kernel(int* __restrict__ meta) {
  if (threadIdx.x < 32) meta[threadIdx.x] = 0;
}

// ---------------------------------------------------------------- gating ----
__global__ void gate_kernel(const float* __restrict__ x, const float* __restrict__ Wg,
                            int* __restrict__ topi, float* __restrict__ topw,
                            int* __restrict__ counts, u16* __restrict__ xb) {
  __shared__ float sWg[DMODEL * NEXP];   // 32 KB
  int tid = threadIdx.x;
  for (int i = tid; i < DMODEL * NEXP / 4; i += 256)
    ((float4*)sWg)[i] = ((const float4*)Wg)[i];
  __syncthreads();

  int wave = tid >> 6, lane = tid & 63;
  int t = blockIdx.x * 4 + wave;       // grid=2048 -> t < 8192 always

  float acc[NEXP] = {0, 0, 0, 0, 0, 0, 0, 0};
  const float* xr = x + (size_t)t * DMODEL;
  u16* xbr = xb + (size_t)t * DMODEL;
  for (int d0 = 0; d0 < DMODEL; d0 += 128) {
    int d = d0 + lane * 2;
    float2 xx = *(const float2*)(xr + d);
    *(uint32_t*)(xbr + d) = (uint32_t)f2bf(xx.x) | ((uint32_t)f2bf(xx.y) << 16);
    const float* g0 = sWg + (size_t)d * NEXP;
#pragma unroll
    for (int e = 0; e < NEXP; e++)
      acc[e] += xx.x * g0[e] + xx.y * g0[NEXP + e];
  }
#pragma unroll
  for (int off = 32; off > 0; off >>= 1)
#pragma unroll
    for (int e = 0; e < NEXP; e++)
      acc[e] += __shfl_xor(acc[e], off, 64);

  if (lane == 0) {
    float v0 = -1e30f, v1 = -1e30f; int i0 = 0, i1 = 0;
#pragma unroll
    for (int e = 0; e < NEXP; e++) {           // strict > keeps earliest index on ties
      float v = acc[e];
      if (v > v0) { v1 = v0; i1 = i0; v0 = v; i0 = e; }
      else if (v > v1) { v1 = v; i1 = e; }
    }
    float e1 = __expf(v1 - v0);                // v1 <= v0
    float s = 1.0f / (1.0f + e1);
    topi[t * 2] = i0; topi[t * 2 + 1] = i1;
    topw[t * 2] = s;  topw[t * 2 + 1] = e1 * s;
    atomicAdd(&counts[i0], 1);
    atomicAdd(&counts[i1], 1);
  }
}

__global__ void scan_kernel(const int* __restrict__ counts, int* __restrict__ offsets,
                            int* __restrict__ cursors) {
  if (threadIdx.x == 0) {
    int s = 0;
    for (int e = 0; e < NEXP; e++) { offsets[e] = s; s += counts[e]; }
    offsets[NEXP] = s;
  }
  if (threadIdx.x < NEXP) cursors[threadIdx.x] = 0;
}

__global__ void build_kernel(const int* __restrict__ topi, const int* __restrict__ offsets,
                             int* __restrict__ cursors, int* __restrict__ perm,
                             int* __restrict__ slotrow) {
  int t = blockIdx.x * blockDim.x + threadIdx.x;
  if (t >= T_TOK) return;
#pragma unroll
  for (int s = 0; s < 2; s++) {
    int e = topi[t * 2 + s];
    int p = atomicAdd(&cursors[e], 1);
    int g = offsets[e] + p;
    perm[g] = t;
    slotrow[t * 2 + s] = g;
  }
}

// ------------------------------------------------------------- transpose ----
__global__ void transpose_kernel(const float* __restrict__ w1, const float* __restrict__ w2,
                                 u16* __restrict__ w1t, u16* __restrict__ w2t) {
  __shared__ u16 sh[64][72];   // +8 pad: keeps 16B store alignment, breaks bank stride
  int z = blockIdx.y;
  const float* src; u16* dst; int R, C;
  if (z < 8) { src = w1 + (size_t)z * (DMODEL * FFN); dst = w1t + (size_t)z * (FFN * DMODEL); R = DMODEL; C = FFN; }
  else       { src = w2 + (size_t)(z - 8) * (FFN * DMODEL); dst = w2t + (size_t)(z - 8) * (DMODEL * FFN); R = FFN; C = DMODEL; }
  int tilesC = C >> 6;
  int rt = blockIdx.x / tilesC, ct = blockIdx.x % tilesC;
  int tid = threadIdx.x;
#pragma unroll
  for (int i = 0; i < 2; i++) {
    int idx = i * 256 + tid;
    int r = idx >> 3, c8 = (idx & 7) * 8;
    const float* s = src + (size_t)(rt * 64 + r) * C + ct * 64 + c8;
    float4 v0 = *(const float4*)s, v1 = *(const float4*)(s + 4);
    u16* d = &sh[r][c8];
    d[0] = f2bf(v0.x); d[1] = f2bf(v0.y); d[2] = f2bf(v0.z); d[3] = f2bf(v0.w);
    d[4] = f2bf(v1.x); d[5] = f2bf(v1.y); d[6] = f2bf(v1.z); d[7] = f2bf(v1.w);
  }
  __syncthreads();
#pragma unroll
  for (int i = 0; i < 2; i++) {
    int idx = i * 256 + tid;
    int c = idx >> 3, r8 = (idx & 7) * 8;
    u16x8 v;
#pragma unroll
    for (int j = 0; j < 8; j++) v[j] = sh[r8 + j][c];
    *(u16x8*)(dst + (size_t)(ct * 64 + c) * R + rt * 64 + r8) = v;
  }
}

// ------------------------------------ GEMM: 256x256, BK=32, quad-buffered ----
// C[i,n] = sum_k Arow(i)[k] * Bt[e][n][k]; A,Bt bf16 K-major.
// R4 redesign: latency-bound diagnosis (9.2k cyc/K-tile vs 620 floor at 1
// block/CU, 2-deep pipeline). BK=32 -> K-tile = 32 KB LDS -> QUAD buffer in
// the same 128 KiB -> prefetch depth 3 K-tiles (~1200 cyc slack > 900 cyc HBM,
// ~96 KB in flight/CU). 2 phases per K-tile (QM halves; B held in regs);
// every LDS byte read exactly once per wave (12 ds_read per 32 MFMA).
// Counted vmcnt derived from the per-thread stream {ph1: B,B,Aq0 (t+3);
// ph2: Aq1 (t+3)}: ph1-end vmcnt(11) lands Aq1(t), ph2-end vmcnt(9) lands
// exactly tile t+1's ph1 material. Swizzle for 64-B rows: physical chunk
// c = kq ^ ((row>>1)&3) (uniform 8 lanes/bank-position); staging source
// chunk (l&3)^((l>>3)&3), valid since all stage row-bases are multiples of 16.
template <int K, int N, bool GATHER, bool GELU>
__global__ __launch_bounds__(512, 2) void gemm4_kernel(
    const u16* __restrict__ A, const u16* __restrict__ Bt, u16* __restrict__ C,
    const int* __restrict__ offsets, const int* __restrict__ perm) {
  __shared__ u16 S[65536];   // A bufs: buf*8192 (4x16KB); B bufs: 32768 + buf*8192
  constexpr int MT  = 32;    // m tiles (covers worst case 8192 rows)
  constexpr int NKT = K / 32;

  // grid = NEXP*NTT*MT; p%8 -> XCD -> expert; slot mtile-fastest (B-panel L2 reuse)
  int p = blockIdx.x;
  int e = p & 7;
  int slot = p >> 3;
  int ntile = slot / MT;
  int mtile = slot % MT;

  int off = offsets[e];
  int nrows = offsets[e + 1] - off;
  if (mtile * 256 >= nrows) return;        // block-uniform: safe before barriers

  int tid = threadIdx.x;
  int w = tid >> 6, l = tid & 63;
  int lm = l & 15, kq = l >> 4;
  int warp_m = w >> 2, warp_n = w & 3;
  int rdcol = (kq ^ ((lm >> 1) & 3)) * 8;      // per-lane swizzled read chunk (u16)
  int scol  = ((l & 3) ^ ((l >> 3) & 3)) * 8;  // per-lane staging source chunk (u16)

  // ---- staging pointers. One async16 covers 16 rows (64 lanes, 4 lanes/row).
  // A region q: lds rows w*16 + (w>>2)*64 + q*64 + (l>>2)  (Q0 = rows 0..63 &
  // 128..191 = QM=0 rows of both warp_m; Q1 = +64). B round i: rows i*128+w*16.
  const u16* aptr[2];
  const u16* bptr[2];
  const u16* bbase = Bt + (size_t)e * ((size_t)N * K);
#pragma unroll
  for (int q = 0; q < 2; q++) {
    int ra = w * 16 + (w >> 2) * 64 + q * 64 + (l >> 2);
    int gm = min(mtile * 256 + ra, nrows - 1);       // clamp: duplicates last row
    int arow = GATHER ? perm[off + gm] : (off + gm);
    aptr[q] = A + (size_t)arow * K + scol;
  }
#pragma unroll
  for (int i = 0; i < 2; i++) {
    int rb = i * 128 + w * 16 + (l >> 2);
    bptr[i] = bbase + (size_t)(ntile * 256 + rb) * K + scol;
  }
  int adst = (w * 16 + (w >> 2) * 64) * 32;    // wave-uniform LDS dest (u16)
  int bdst = 32768 + (w * 16) * 32;

#define STAGE_B(buf, kt) do {                                                  \
    async16(bptr[0] + (kt) * 32, S + (buf) * 8192 + bdst);                     \
    async16(bptr[1] + (kt) * 32, S + (buf) * 8192 + bdst + 128 * 32);          \
  } while (0)
#define STAGE_A(q, buf, kt)                                                    \
    async16(aptr[q] + (kt) * 32, S + (buf) * 8192 + adst + (q) * 64 * 32)

  f32x4 acc[8][4];
  f32x4 zero = {0.f, 0.f, 0.f, 0.f};
#pragma unroll
  for (int i = 0; i < 8; i++)
#pragma unroll
    for (int j = 0; j < 4; j++) acc[i][j] = zero;

  short8 a[4], b[4];

#define RD_A(buf, QM)                                                          \
  _Pragma("unroll") for (int fi = 0; fi < 4; fi++) {                           \
    int row = warp_m * 128 + (QM) * 64 + fi * 16 + lm;                         \
    a[fi] = *(const short8*)(S + (buf) * 8192 + row * 32 + rdcol);             \
  }
#define RD_B(buf)                                                              \
  _Pragma("unroll") for (int nj = 0; nj < 4; nj++) {                           \
    int row = warp_n * 64 + nj * 16 + lm;                                      \
    b[nj] = *(const short8*)(S + 32768 + (buf) * 8192 + row * 32 + rdcol);     \
  }
// barrier -> wait this phase's ds_reads -> fence (rule #18) -> prio MFMA x16
#define MM(QM)                                                                 \
  __builtin_amdgcn_s_barrier();                                                \
  asm volatile("s_waitcnt lgkmcnt(0)" ::: "memory");                           \
  __builtin_amdgcn_sched_barrier(0);                                           \
  __builtin_amdgcn_s_setprio(1);                                               \
  _Pragma("unroll") for (int fi = 0; fi < 4; fi++)                             \
    _Pragma("unroll") for (int nj = 0; nj < 4; nj++)                           \
      acc[(QM) * 4 + fi][nj] = __builtin_amdgcn_mfma_f32_16x16x32_bf16(        \
          a[fi], b[nj], acc[(QM) * 4 + fi][nj], 0, 0, 0);                      \
  __builtin_amdgcn_s_setprio(0);

  // ---- prologue: stage tiles 0..2 (12 instrs); vmcnt(9) = tile0's {B,B,Aq0}
  // landed, Aq1(0) + tiles 1,2 (9 instrs) in flight — steady-state aging.
#pragma unroll
  for (int t0 = 0; t0 < 3; t0++) {
    int kt = t0 < NKT ? t0 : NKT - 1;
    STAGE_B(t0 & 3, kt);
    STAGE_A(0, t0 & 3, kt);
    STAGE_A(1, t0 & 3, kt);
  }
  asm volatile("s_waitcnt vmcnt(9)" ::: "memory");
  __builtin_amdgcn_s_barrier();

  for (int t = 0; t < NKT; t++) {
    int buf = t & 3, sbuf = (t + 3) & 3;       // sbuf's content (t-1) fully dead
    int kt3 = min(t + 3, NKT - 1);             // clamp keeps vmcnt counts exact
    // ph1: read B + A-q0 of tile t; stage {B, A-q0} of t+3
    RD_B(buf)
    RD_A(buf, 0)
    STAGE_B(sbuf, kt3);
    STAGE_A(0, sbuf, kt3);
    MM(0)
    asm volatile("s_waitcnt vmcnt(11)" ::: "memory");   // lands Aq1(t) for ph2
    __builtin_amdgcn_s_barrier();
    // ph2: read A-q1 of tile t (B held in regs); stage A-q1 of t+3
    RD_A(buf, 1)
    STAGE_A(1, sbuf, kt3);
    MM(1)
    asm volatile("s_waitcnt vmcnt(9)" ::: "memory");    // lands {B,Aq0}(t+1)
    __builtin_amdgcn_s_barrier();
  }

  asm volatile("s_waitcnt vmcnt(0)" ::: "memory");   // drain LDS-DMA before exit

  // C/D frag: col = lane&15, row = (lane>>4)*4 + reg
#pragma unroll
  for (int fi = 0; fi < 8; fi++) {
    int rowb = mtile * 256 + warp_m * 128 + fi * 16 + kq * 4;
#pragma unroll
    for (int r = 0; r < 4; r++) {
      int row = rowb + r;
      if (row < nrows) {
        u16* crow = C + (size_t)(off + row) * N + ntile * 256 + warp_n * 64 + lm;
#pragma unroll
        for (int fj = 0; fj < 4; fj++) {
          float v = acc[fi][fj][r];
          if (GELU) v = gelu_tanh(v);
          crow[fj * 16] = f2bf(v);
        }
      }
    }
  }
#undef STAGE_A
#undef STAGE_B
#undef RD_A
#undef RD_B
#undef MM
}

// --------------------------------------------- GEMM (fallback, fp32 B) -----
template <int K, int N, bool GATHER, bool GELU>
__global__ __launch_bounds__(256) void gemm_f_kernel(
    const u16* __restrict__ A, const float* __restrict__ B, u16* __restrict__ C,
    const int* __restrict__ offsets, const int* __restrict__ perm) {
  __shared__ u16 As[128 * 32];
  __shared__ u16 Bs[128 * 32];
  int e = blockIdx.z;
  int off = offsets[e];
  int nrows = offsets[e + 1] - off;
  int mtile = blockIdx.y;
  if (mtile * 128 >= nrows) return;
  int ntile = blockIdx.x;

  int tid = threadIdx.x;
  int wave = tid >> 6, lane = tid & 63;

  int rr = tid >> 2;
  int kc = (tid & 3) * 8;
  int m0 = mtile * 128 + rr;
  int mm0 = min(m0, nrows - 1);
  int mm1 = min(m0 + 64, nrows - 1);
  const u16 *arow0, *arow1;
  if (GATHER) {
    arow0 = A + (size_t)perm[off + mm0] * K + kc;
    arow1 = A + (size_t)perm[off + mm1] * K + kc;
  } else {
    arow0 = A + (size_t)(off + mm0) * K + kc;
    arow1 = A + (size_t)(off + mm1) * K + kc;
  }

  int kk2 = (tid >> 4) * 2;
  int n8  = (tid & 15) * 8;
  const float* brow0 = B + (size_t)e * ((size_t)K * N) + (size_t)kk2 * N
                         + (size_t)ntile * 128 + n8;
  const float* brow1 = brow0 + N;

  int wm = (wave >> 1) * 64, wn = (wave & 1) * 64;
  int lm = lane & 15, kq = lane >> 4;

  f32x4 acc[4][4];
  f32x4 zero = {0.f, 0.f, 0.f, 0.f};
#pragma unroll
  for (int i = 0; i < 4; i++)
#pragma unroll
    for (int j = 0; j < 4; j++) acc[i][j] = zero;

  uint32_t* bs32 = (uint32_t*)Bs;
  for (int k0 = 0; k0 < K; k0 += 32) {
    u16x8 av0 = *(const u16x8*)(arow0 + k0);
    u16x8 av1 = *(const u16x8*)(arow1 + k0);
    float4 b00 = *(const float4*)(brow0 + (size_t)k0 * N);
    float4 b01 = *(const float4*)(brow0 + (size_t)k0 * N + 4);
    float4 b10 = *(const float4*)(brow1 + (size_t)k0 * N);
    float4 b11 = *(const float4*)(brow1 + (size_t)k0 * N + 4);
    __syncthreads();
    *(u16x8*)(As + (size_t)rr * 32 + kc) = av0;
    *(u16x8*)(As + (size_t)(rr + 64) * 32 + kc) = av1;
    int wcol = kk2 >> 1;
    bs32[(size_t)(n8 + 0) * 16 + wcol] = (uint32_t)f2bf(b00.x) | ((uint32_t)f2bf(b10.x) << 16);
    bs32[(size_t)(n8 + 1) * 16 + wcol] = (uint32_t)f2bf(b00.y) | ((uint32_t)f2bf(b10.y) << 16);
    bs32[(size_t)(n8 + 2) * 16 + wcol] = (uint32_t)f2bf(b00.z) | ((uint32_t)f2bf(b10.z) << 16);
    bs32[(size_t)(n8 + 3) * 16 + wcol] = (uint32_t)f2bf(b00.w) | ((uint32_t)f2bf(b10.w) << 16);
    bs32[(size_t)(n8 + 4) * 16 + wcol] = (uint32_t)f2bf(b01.x) | ((uint32_t)f2bf(b11.x) << 16);
    bs32[(size_t)(n8 + 5) * 16 + wcol] = (uint32_t)f2bf(b01.y) | ((uint32_t)f2bf(b11.y) << 16);
    bs32[(size_t)(n8 + 6) * 16 + wcol] = (uint32_t)f2bf(b01.z) | ((uint32_t)f2bf(b11.z) << 16);
    bs32[(size_t)(n8 + 7) * 16 + wcol] = (uint32_t)f2bf(b01.w) | ((uint32_t)f2bf(b11.w) << 16);
    __syncthreads();
    short8 a[4], b[4];
#pragma unroll
    for (int i = 0; i < 4; i++) {
      a[i] = *(const short8*)(As + (size_t)(wm + i * 16 + lm) * 32 + kq * 8);
      b[i] = *(const short8*)(Bs + (size_t)(wn + i * 16 + lm) * 32 + kq * 8);
    }
#pragma unroll
    for (int i = 0; i < 4; i++)
#pragma unroll
      for (int j = 0; j < 4; j++)
        acc[i][j] = __builtin_amdgcn_mfma_f32_16x16x32_bf16(a[i], b[j], acc[i][j], 0, 0, 0);
  }

#pragma unroll
  for (int i = 0; i < 4; i++) {
    int rbase = mtile * 128 + wm + i * 16 + kq * 4;
#pragma unroll
    for (int r = 0; r < 4; r++) {
      int row = rbase + r;
      if (row < nrows) {
        u16* crow = C + (size_t)(off + row) * N + ntile * 128 + wn + lm;
#pragma unroll
        for (int j = 0; j < 4; j++) {
          float v = acc[i][j][r];
          if (GELU) v = gelu_tanh(v);
          crow[j * 16] = f2bf(v);
        }
      }
    }
  }
}

// --------------------------------------------------------------- combine ----
__global__ void combine_kernel(const u16* __restrict__ Y, const int* __restrict__ slotrow,
                               const float* __restrict__ topw, float* __restrict__ out) {
  int idx = blockIdx.x * 256 + threadIdx.x;   // 8192 tokens * 256 chunks of 4
  int t = idx >> 8;
  int c = (idx & 255) * 4;
  int g0 = slotrow[t * 2], g1 = slotrow[t * 2 + 1];
  float w0 = topw[t * 2], w1 = topw[t * 2 + 1];
  u16x4 y0 = *(const u16x4*)(Y + (size_t)g0 * DMODEL + c);
  u16x4 y1 = *(const u16x4*)(Y + (size_t)g1 * DMODEL + c);
  float4 o;
  o.x = w0 * bf2f(y0[0]) + w1 * bf2f(y1[0]);
  o.y = w0 * bf2f(y0[1]) + w1 * bf2f(y1[1]);
  o.z = w0 * bf2f(y0[2]) + w1 * bf2f(y1[2]);
  o.w = w0 * bf2f(y0[3]) + w1 * bf2f(y1[3]);
  *(float4*)(out + (size_t)t * DMODEL + c) = o;
}

// ---------------------------------------------------------------- launch ----
extern "C" void kernel_launch(void* const* d_in, const int* in_sizes, int n_in,
                              void* d_out, int out_size, void* d_ws, size_t ws_size,
                              hipStream_t stream) {
  const float* x  = (const float*)d_in[0];
  const float* Wg = (const float*)d_in[1];
  const float* w1 = (const float*)d_in[2];
  const float* w2 = (const float*)d_in[3];
  float* out = (float*)d_out;

  const size_t SZ_H   = (size_t)TASSIGN * FFN * 2;        // 128 MB
  const size_t SZ_W1T = (size_t)NEXP * FFN * DMODEL * 2;  //  64 MB (Y aliases: needs 32 MB)
  const size_t SZ_W2T = (size_t)NEXP * DMODEL * FFN * 2;  //  64 MB
  const size_t SZ_XB  = (size_t)T_TOK * DMODEL * 2;       //  16 MB
  const size_t SZ_Y   = (size_t)TASSIGN * DMODEL * 2;     //  32 MB
  const size_t SZ_SMALL = (size_t)TASSIGN * 4 * 4 + 4096;
  const size_t WS_FULL = SZ_H + SZ_W1T + SZ_W2T + SZ_XB + SZ_SMALL;   // ~272.3 MB

  uint8_t* ws = (uint8_t*)d_ws;
  bool fast = (ws_size >= WS_FULL);

  size_t o = 0;
  u16* H = (u16*)(ws + o); o += SZ_H;
  u16 *w1t = nullptr, *w2t = nullptr, *Y;
  if (fast) {
    w1t = (u16*)(ws + o); o += SZ_W1T;
    w2t = (u16*)(ws + o); o += SZ_W2T;
    Y = w1t;                       // w1t is dead once GEMM2 starts writing Y
  } else {
    Y = (u16*)(ws + o); o += SZ_Y;
  }
  u16* xb = (u16*)(ws + o); o += SZ_XB;
  int*   topi    = (int*)(ws + o);   o += (size_t)TASSIGN * 4;
  float* topw    = (float*)(ws + o); o += (size_t)TASSIGN * 4;
  int*   perm    = (int*)(ws + o);   o += (size_t)TASSIGN * 4;
  int*   slotrow = (int*)(ws + o);   o += (size_t)TASSIGN * 4;
  int*   meta    = (int*)(ws + o);
  int* counts = meta, *offsets = meta + 8, *cursors = meta + 17;

  init_kernel<<<1, 64, 0, stream>>>(meta);
  gate_kernel<<<T_TOK / 4, 256, 0, stream>>>(x, Wg, topi, topw, counts, xb);
  scan_kernel<<<1, 64, 0, stream>>>(counts, offsets, cursors);
  build_kernel<<<T_TOK / 256, 256, 0, stream>>>(topi, offsets, cursors, perm, slotrow);

  if (fast) {
    transpose_kernel<<<dim3(1024, 16), 256, 0, stream>>>(w1, w2, w1t, w2t);
    // grid = NEXP * (N/256) * 32, 512 threads, XCD/expert-affine swizzle inside
    gemm4_kernel<DMODEL, FFN, true, true>
        <<<NEXP * (FFN / 256) * 32, 512, 0, stream>>>(xb, w1t, H, offsets, perm);
    gemm4_kernel<FFN, DMODEL, false, false>
        <<<NEXP * (DMODEL / 256) * 32, 512, 0, stream>>>(H, w2t, Y, offsets, perm);
  } else {
    gemm_f_kernel<DMODEL, FFN, true, true>
        <<<dim3(FFN / 128, 64, NEXP), 256, 0, stream>>>(xb, w1, H, offsets, perm);
    gemm_f_kernel<FFN, DMODEL, false, false>
        <<<dim3(DMODEL / 128, 64, NEXP), 256, 0, stream>>>(H, w2, Y, offsets, perm);
  }
  combine_kernel<<<(T_TOK * DMODEL / 4) / 256, 256, 0, stream>>>(Y, slotrow, topw, out);
}

// Round 5
// 1015.116 us; speedup vs baseline: 1.0420x; 1.0420x over previous
//
#include <hip/hip_runtime.h>
#include <stdint.h>

// Problem constants: B=4, S=2048, D=1024, E=8, F=4096, k=2 — FP32 I/O, bf16 MFMA compute
#define T_TOK   8192
#define DMODEL  1024
#define NEXP    8
#define FFN     4096
#define TASSIGN 16384   // T_TOK * k

typedef unsigned short u16;
typedef __attribute__((ext_vector_type(8))) short short8;   // MFMA bf16 A/B frag
typedef __attribute__((ext_vector_type(8))) u16 u16x8;
typedef __attribute__((ext_vector_type(4))) u16 u16x4;
typedef __attribute__((ext_vector_type(4))) float f32x4;    // MFMA C/D frag

__device__ __forceinline__ float bf2f(u16 u) {
  union { unsigned int i; float f; } v; v.i = ((unsigned int)u) << 16; return v.f;
}
__device__ __forceinline__ u16 f2bf(float f) {
  union { float f; unsigned int i; } v; v.f = f;
  unsigned int x = v.i;
  x += 0x7fffu + ((x >> 16) & 1u);   // round-to-nearest-even
  return (u16)(x >> 16);
}
// jax.nn.gelu default: approximate=True (tanh form)
__device__ __forceinline__ float gelu_tanh(float x) {
  float z = 0.7978845608028654f * x * (1.0f + 0.044715f * x * x);
  float t = 1.0f - 2.0f / (__expf(2.0f * z) + 1.0f);
  return 0.5f * x * (1.0f + t);
}
// async global->LDS, 16B per lane; LDS dest is wave-uniform base + lane*16
__device__ __forceinline__ void async16(const void* g, void* l) {
  __builtin_amdgcn_global_load_lds((__attribute__((address_space(1))) void*)g,
                                   (__attribute__((address_space(3))) void*)l,
                                   16, 0, 0);
}

// ---------------------------------------------------------------- meta init --
__global__ void init_kernel(int* __restrict__ meta) {
  if (threadIdx.x < 32) meta[threadIdx.x] = 0;
}

// ---------------------------------------------------------------- gating ----
__global__ void gate_kernel(const float* __restrict__ x, const float* __restrict__ Wg,
                            int* __restrict__ topi, float* __restrict__ topw,
                            int* __restrict__ counts, u16* __restrict__ xb) {
  __shared__ float sWg[DMODEL * NEXP];   // 32 KB
  int tid = threadIdx.x;
  for (int i = tid; i < DMODEL * NEXP / 4; i += 256)
    ((float4*)sWg)[i] = ((const float4*)Wg)[i];
  __syncthreads();

  int wave = tid >> 6, lane = tid & 63;
  int t = blockIdx.x * 4 + wave;       // grid=2048 -> t < 8192 always

  float acc[NEXP] = {0, 0, 0, 0, 0, 0, 0, 0};
  const float* xr = x + (size_t)t * DMODEL;
  u16* xbr = xb + (size_t)t * DMODEL;
  for (int d0 = 0; d0 < DMODEL; d0 += 128) {
    int d = d0 + lane * 2;
    float2 xx = *(const float2*)(xr + d);
    *(uint32_t*)(xbr + d) = (uint32_t)f2bf(xx.x) | ((uint32_t)f2bf(xx.y) << 16);
    const float* g0 = sWg + (size_t)d * NEXP;
#pragma unroll
    for (int e = 0; e < NEXP; e++)
      acc[e] += xx.x * g0[e] + xx.y * g0[NEXP + e];
  }
#pragma unroll
  for (int off = 32; off > 0; off >>= 1)
#pragma unroll
    for (int e = 0; e < NEXP; e++)
      acc[e] += __shfl_xor(acc[e], off, 64);

  if (lane == 0) {
    float v0 = -1e30f, v1 = -1e30f; int i0 = 0, i1 = 0;
#pragma unroll
    for (int e = 0; e < NEXP; e++) {           // strict > keeps earliest index on ties
      float v = acc[e];
      if (v > v0) { v1 = v0; i1 = i0; v0 = v; i0 = e; }
      else if (v > v1) { v1 = v; i1 = e; }
    }
    float e1 = __expf(v1 - v0);                // v1 <= v0
    float s = 1.0f / (1.0f + e1);
    topi[t * 2] = i0; topi[t * 2 + 1] = i1;
    topw[t * 2] = s;  topw[t * 2 + 1] = e1 * s;
    atomicAdd(&counts[i0], 1);
    atomicAdd(&counts[i1], 1);
  }
}

__global__ void scan_kernel(const int* __restrict__ counts, int* __restrict__ offsets,
                            int* __restrict__ cursors) {
  if (threadIdx.x == 0) {
    int s = 0;
    for (int e = 0; e < NEXP; e++) { offsets[e] = s; s += counts[e]; }
    offsets[NEXP] = s;
  }
  if (threadIdx.x < NEXP) cursors[threadIdx.x] = 0;
}

__global__ void build_kernel(const int* __restrict__ topi, const int* __restrict__ offsets,
                             int* __restrict__ cursors, int* __restrict__ perm,
                             int* __restrict__ slotrow) {
  int t = blockIdx.x * blockDim.x + threadIdx.x;
  if (t >= T_TOK) return;
#pragma unroll
  for (int s = 0; s < 2; s++) {
    int e = topi[t * 2 + s];
    int p = atomicAdd(&cursors[e], 1);
    int g = offsets[e] + p;
    perm[g] = t;
    slotrow[t * 2 + s] = g;
  }
}

// ------------------------------------------------------------- transpose ----
// fp32 -> bf16 + transpose, 64x64 tiles. LDS: [64][64] u16 linear, chunk-XOR
// swizzle keyed on (row>>3): phys chunk = logical ^ ((row>>3)&7). Writes are
// vectorized u16x8 (16B aligned); reads (8 rows x 1 col per thread) hit 8
// distinct bank groups (old +8-pad layout had lane stride 8 rows = 1152 B ==
// 0 mod 32 banks -> 8-way conflict).
__global__ void transpose_kernel(const float* __restrict__ w1, const float* __restrict__ w2,
                                 u16* __restrict__ w1t, u16* __restrict__ w2t) {
  __shared__ u16 sh[64 * 64];
  int z = blockIdx.y;
  const float* src; u16* dst; int R, C;
  if (z < 8) { src = w1 + (size_t)z * (DMODEL * FFN); dst = w1t + (size_t)z * (FFN * DMODEL); R = DMODEL; C = FFN; }
  else       { src = w2 + (size_t)(z - 8) * (FFN * DMODEL); dst = w2t + (size_t)(z - 8) * (DMODEL * FFN); R = FFN; C = DMODEL; }
  int tilesC = C >> 6;
  int rt = blockIdx.x / tilesC, ct = blockIdx.x % tilesC;
  int tid = threadIdx.x;
#pragma unroll
  for (int i = 0; i < 2; i++) {
    int idx = i * 256 + tid;
    int r = idx >> 3, c8 = idx & 7;
    const float* s = src + (size_t)(rt * 64 + r) * C + ct * 64 + c8 * 8;
    float4 v0 = *(const float4*)s, v1 = *(const float4*)(s + 4);
    u16x8 pk;
    pk[0] = f2bf(v0.x); pk[1] = f2bf(v0.y); pk[2] = f2bf(v0.z); pk[3] = f2bf(v0.w);
    pk[4] = f2bf(v1.x); pk[5] = f2bf(v1.y); pk[6] = f2bf(v1.z); pk[7] = f2bf(v1.w);
    *(u16x8*)(sh + r * 64 + ((c8 ^ ((r >> 3) & 7)) * 8)) = pk;
  }
  __syncthreads();
#pragma unroll
  for (int i = 0; i < 2; i++) {
    int idx = i * 256 + tid;
    int c = idx >> 3, r8 = (idx & 7) * 8;
    int chunk = (c >> 3) ^ (idx & 7);          // ((r8+j)>>3)&7 == idx&7
    u16x8 v;
#pragma unroll
    for (int j = 0; j < 8; j++) v[j] = sh[(r8 + j) * 64 + chunk * 8 + (c & 7)];
    *(u16x8*)(dst + (size_t)(ct * 64 + c) * R + rt * 64 + r8) = v;
  }
}

// ------------------------------------------------------- GEMM (fast path) ----
// C[i,n] = sum_k Arow(i)[k] * Bt[e][n][k]; A,Bt bf16 (Bt = K-major weights).
// R0's verified m97 structure (BM=BN=128, BK=32, 256 thr, 2-barrier loop,
// global_load_lds width 16) + two session-proven fixes:
//  1. chunk-XOR LDS swizzle (R4-verified zero-conflict pair on 32-u16 rows):
//     read chunk = kq ^ ((row>>1)&3); staging source chunk pre-swizzled
//     (tid&3)^((tid>>3)&3), LDS dest stays linear (rule #21).
//  2. expert<->XCD affinity grid (p%8 = expert = XCD; R1-R4: FETCH 630->~140MB).
//     NFAST picks slot order: GEMM1 mtile-fastest (A fits L2, B streamed once);
//     GEMM2 ntile-fastest (A=16MB/expert fetched once, B re-fetched 4x).
template <int K, int N, bool GATHER, bool GELU, bool NFAST>
__global__ __launch_bounds__(256) void gemm_t_kernel(
    const u16* __restrict__ A, const u16* __restrict__ Bt, u16* __restrict__ C,
    const int* __restrict__ offsets, const int* __restrict__ perm) {
  __shared__ u16 As[128 * 32];   // [row][k] 8 KB (chunk-swizzled)
  __shared__ u16 Bs[128 * 32];   // [n][k]   8 KB
  constexpr int NT = N / 128;
  constexpr int MT = 64;         // covers worst-case 8192 rows/expert

  int p = blockIdx.x;
  int e = p & 7;
  int slot = p >> 3;
  int ntile, mtile;
  if (NFAST) { ntile = slot % NT; mtile = slot / NT; }
  else       { mtile = slot % MT; ntile = slot / MT; }

  int off = offsets[e];
  int nrows = offsets[e + 1] - off;
  if (mtile * 128 >= nrows) return;   // block-uniform: safe before barriers

  int tid = threadIdx.x;
  int wave = tid >> 6, lane = tid & 63;

  int rr = tid >> 2;                              // tile row of this thread's chunk
  int kc = ((tid & 3) ^ ((tid >> 3) & 3)) * 8;    // pre-swizzled source k-chunk

  int m0 = mtile * 128 + rr;
  int mm0 = min(m0, nrows - 1);          // clamp: duplicates last valid row
  int mm1 = min(m0 + 64, nrows - 1);
  const u16 *arow0, *arow1;
  if (GATHER) {
    arow0 = A + (size_t)perm[off + mm0] * K + kc;
    arow1 = A + (size_t)perm[off + mm1] * K + kc;
  } else {
    arow0 = A + (size_t)(off + mm0) * K + kc;
    arow1 = A + (size_t)(off + mm1) * K + kc;
  }
  const u16* bbase = Bt + (size_t)e * ((size_t)N * K);
  const u16* brow0 = bbase + (size_t)(ntile * 128 + rr) * K + kc;
  const u16* brow1 = bbase + (size_t)(ntile * 128 + rr + 64) * K + kc;

  // wave-uniform LDS destinations: chunk index == tid (and tid+256), linear
  u16* asd0 = As + (size_t)(wave * 64) * 8;
  u16* asd1 = As + (size_t)(256 + wave * 64) * 8;
  u16* bsd0 = Bs + (size_t)(wave * 64) * 8;
  u16* bsd1 = Bs + (size_t)(256 + wave * 64) * 8;

  int wm = (wave >> 1) * 64, wn = (wave & 1) * 64;
  int lm = lane & 15, kq = lane >> 4;
  int rdc = (kq ^ ((lm >> 1) & 3)) * 8;   // swizzled read chunk (row>>1 == lm>>1 mod 4)

  f32x4 acc[4][4];
  f32x4 zero = {0.f, 0.f, 0.f, 0.f};
#pragma unroll
  for (int i = 0; i < 4; i++)
#pragma unroll
    for (int j = 0; j < 4; j++) acc[i][j] = zero;

  for (int k0 = 0; k0 < K; k0 += 32) {
    async16(arow0 + k0, asd0);
    async16(arow1 + k0, asd1);
    async16(brow0 + k0, bsd0);
    async16(brow1 + k0, bsd1);
    __syncthreads();   // drains vmcnt -> staged tile visible
    short8 a[4], b[4];
#pragma unroll
    for (int i = 0; i < 4; i++) {
      a[i] = *(const short8*)(As + (size_t)(wm + i * 16 + lm) * 32 + rdc);
      b[i] = *(const short8*)(Bs + (size_t)(wn + i * 16 + lm) * 32 + rdc);
    }
#pragma unroll
    for (int i = 0; i < 4; i++)
#pragma unroll
      for (int j = 0; j < 4; j++)
        acc[i][j] = __builtin_amdgcn_mfma_f32_16x16x32_bf16(a[i], b[j], acc[i][j], 0, 0, 0);
    __syncthreads();   // protect LDS from next iteration's staging
  }

  // C/D frag: col = lane&15, row = (lane>>4)*4 + reg
#pragma unroll
  for (int i = 0; i < 4; i++) {
    int rbase = mtile * 128 + wm + i * 16 + kq * 4;
#pragma unroll
    for (int r = 0; r < 4; r++) {
      int row = rbase + r;
      if (row < nrows) {
        u16* crow = C + (size_t)(off + row) * N + ntile * 128 + wn + lm;
#pragma unroll
        for (int j = 0; j < 4; j++) {
          float v = acc[i][j][r];
          if (GELU) v = gelu_tanh(v);
          crow[j * 16] = f2bf(v);
        }
      }
    }
  }
}

// --------------------------------------------- GEMM (fallback, fp32 B) -----
template <int K, int N, bool GATHER, bool GELU>
__global__ __launch_bounds__(256) void gemm_f_kernel(
    const u16* __restrict__ A, const float* __restrict__ B, u16* __restrict__ C,
    const int* __restrict__ offsets, const int* __restrict__ perm) {
  __shared__ u16 As[128 * 32];
  __shared__ u16 Bs[128 * 32];
  int e = blockIdx.z;
  int off = offsets[e];
  int nrows = offsets[e + 1] - off;
  int mtile = blockIdx.y;
  if (mtile * 128 >= nrows) return;
  int ntile = blockIdx.x;

  int tid = threadIdx.x;
  int wave = tid >> 6, lane = tid & 63;

  int rr = tid >> 2;
  int kc = (tid & 3) * 8;
  int m0 = mtile * 128 + rr;
  int mm0 = min(m0, nrows - 1);
  int mm1 = min(m0 + 64, nrows - 1);
  const u16 *arow0, *arow1;
  if (GATHER) {
    arow0 = A + (size_t)perm[off + mm0] * K + kc;
    arow1 = A + (size_t)perm[off + mm1] * K + kc;
  } else {
    arow0 = A + (size_t)(off + mm0) * K + kc;
    arow1 = A + (size_t)(off + mm1) * K + kc;
  }

  int kk2 = (tid >> 4) * 2;
  int n8  = (tid & 15) * 8;
  const float* brow0 = B + (size_t)e * ((size_t)K * N) + (size_t)kk2 * N
                         + (size_t)ntile * 128 + n8;
  const float* brow1 = brow0 + N;

  int wm = (wave >> 1) * 64, wn = (wave & 1) * 64;
  int lm = lane & 15, kq = lane >> 4;

  f32x4 acc[4][4];
  f32x4 zero = {0.f, 0.f, 0.f, 0.f};
#pragma unroll
  for (int i = 0; i < 4; i++)
#pragma unroll
    for (int j = 0; j < 4; j++) acc[i][j] = zero;

  uint32_t* bs32 = (uint32_t*)Bs;
  for (int k0 = 0; k0 < K; k0 += 32) {
    u16x8 av0 = *(const u16x8*)(arow0 + k0);
    u16x8 av1 = *(const u16x8*)(arow1 + k0);
    float4 b00 = *(const float4*)(brow0 + (size_t)k0 * N);
    float4 b01 = *(const float4*)(brow0 + (size_t)k0 * N + 4);
    float4 b10 = *(const float4*)(brow1 + (size_t)k0 * N);
    float4 b11 = *(const float4*)(brow1 + (size_t)k0 * N + 4);
    __syncthreads();
    *(u16x8*)(As + (size_t)rr * 32 + kc) = av0;
    *(u16x8*)(As + (size_t)(rr + 64) * 32 + kc) = av1;
    int wcol = kk2 >> 1;
    bs32[(size_t)(n8 + 0) * 16 + wcol] = (uint32_t)f2bf(b00.x) | ((uint32_t)f2bf(b10.x) << 16);
    bs32[(size_t)(n8 + 1) * 16 + wcol] = (uint32_t)f2bf(b00.y) | ((uint32_t)f2bf(b10.y) << 16);
    bs32[(size_t)(n8 + 2) * 16 + wcol] = (uint32_t)f2bf(b00.z) | ((uint32_t)f2bf(b10.z) << 16);
    bs32[(size_t)(n8 + 3) * 16 + wcol] = (uint32_t)f2bf(b00.w) | ((uint32_t)f2bf(b10.w) << 16);
    bs32[(size_t)(n8 + 4) * 16 + wcol] = (uint32_t)f2bf(b01.x) | ((uint32_t)f2bf(b11.x) << 16);
    bs32[(size_t)(n8 + 5) * 16 + wcol] = (uint32_t)f2bf(b01.y) | ((uint32_t)f2bf(b11.y) << 16);
    bs32[(size_t)(n8 + 6) * 16 + wcol] = (uint32_t)f2bf(b01.z) | ((uint32_t)f2bf(b11.z) << 16);
    bs32[(size_t)(n8 + 7) * 16 + wcol] = (uint32_t)f2bf(b01.w) | ((uint32_t)f2bf(b11.w) << 16);
    __syncthreads();
    short8 a[4], b[4];
#pragma unroll
    for (int i = 0; i < 4; i++) {
      a[i] = *(const short8*)(As + (size_t)(wm + i * 16 + lm) * 32 + kq * 8);
      b[i] = *(const short8*)(Bs + (size_t)(wn + i * 16 + lm) * 32 + kq * 8);
    }
#pragma unroll
    for (int i = 0; i < 4; i++)
#pragma unroll
      for (int j = 0; j < 4; j++)
        acc[i][j] = __builtin_amdgcn_mfma_f32_16x16x32_bf16(a[i], b[j], acc[i][j], 0, 0, 0);
  }

#pragma unroll
  for (int i = 0; i < 4; i++) {
    int rbase = mtile * 128 + wm + i * 16 + kq * 4;
#pragma unroll
    for (int r = 0; r < 4; r++) {
      int row = rbase + r;
      if (row < nrows) {
        u16* crow = C + (size_t)(off + row) * N + ntile * 128 + wn + lm;
#pragma unroll
        for (int j = 0; j < 4; j++) {
          float v = acc[i][j][r];
          if (GELU) v = gelu_tanh(v);
          crow[j * 16] = f2bf(v);
        }
      }
    }
  }
}

// --------------------------------------------------------------- combine ----
__global__ void combine_kernel(const u16* __restrict__ Y, const int* __restrict__ slotrow,
                               const float* __restrict__ topw, float* __restrict__ out) {
  int idx = blockIdx.x * 256 + threadIdx.x;   // 8192 tokens * 256 chunks of 4
  int t = idx >> 8;
  int c = (idx & 255) * 4;
  int g0 = slotrow[t * 2], g1 = slotrow[t * 2 + 1];
  float w0 = topw[t * 2], w1 = topw[t * 2 + 1];
  u16x4 y0 = *(const u16x4*)(Y + (size_t)g0 * DMODEL + c);
  u16x4 y1 = *(const u16x4*)(Y + (size_t)g1 * DMODEL + c);
  float4 o;
  o.x = w0 * bf2f(y0[0]) + w1 * bf2f(y1[0]);
  o.y = w0 * bf2f(y0[1]) + w1 * bf2f(y1[1]);
  o.z = w0 * bf2f(y0[2]) + w1 * bf2f(y1[2]);
  o.w = w0 * bf2f(y0[3]) + w1 * bf2f(y1[3]);
  *(float4*)(out + (size_t)t * DMODEL + c) = o;
}

// ---------------------------------------------------------------- launch ----
extern "C" void kernel_launch(void* const* d_in, const int* in_sizes, int n_in,
                              void* d_out, int out_size, void* d_ws, size_t ws_size,
                              hipStream_t stream) {
  const float* x  = (const float*)d_in[0];
  const float* Wg = (const float*)d_in[1];
  const float* w1 = (const float*)d_in[2];
  const float* w2 = (const float*)d_in[3];
  float* out = (float*)d_out;

  const size_t SZ_H   = (size_t)TASSIGN * FFN * 2;        // 128 MB
  const size_t SZ_W1T = (size_t)NEXP * FFN * DMODEL * 2;  //  64 MB (Y aliases: needs 32 MB)
  const size_t SZ_W2T = (size_t)NEXP * DMODEL * FFN * 2;  //  64 MB
  const size_t SZ_XB  = (size_t)T_TOK * DMODEL * 2;       //  16 MB
  const size_t SZ_Y   = (size_t)TASSIGN * DMODEL * 2;     //  32 MB
  const size_t SZ_SMALL = (size_t)TASSIGN * 4 * 4 + 4096;
  const size_t WS_FULL = SZ_H + SZ_W1T + SZ_W2T + SZ_XB + SZ_SMALL;   // ~272.3 MB

  uint8_t* ws = (uint8_t*)d_ws;
  bool fast = (ws_size >= WS_FULL);

  size_t o = 0;
  u16* H = (u16*)(ws + o); o += SZ_H;
  u16 *w1t = nullptr, *w2t = nullptr, *Y;
  if (fast) {
    w1t = (u16*)(ws + o); o += SZ_W1T;
    w2t = (u16*)(ws + o); o += SZ_W2T;
    Y = w1t;                       // w1t is dead once GEMM2 starts writing Y
  } else {
    Y = (u16*)(ws + o); o += SZ_Y;
  }
  u16* xb = (u16*)(ws + o); o += SZ_XB;
  int*   topi    = (int*)(ws + o);   o += (size_t)TASSIGN * 4;
  float* topw    = (float*)(ws + o); o += (size_t)TASSIGN * 4;
  int*   perm    = (int*)(ws + o);   o += (size_t)TASSIGN * 4;
  int*   slotrow = (int*)(ws + o);   o += (size_t)TASSIGN * 4;
  int*   meta    = (int*)(ws + o);
  int* counts = meta, *offsets = meta + 8, *cursors = meta + 17;

  init_kernel<<<1, 64, 0, stream>>>(meta);
  gate_kernel<<<T_TOK / 4, 256, 0, stream>>>(x, Wg, topi, topw, counts, xb);
  scan_kernel<<<1, 64, 0, stream>>>(counts, offsets, cursors);
  build_kernel<<<T_TOK / 256, 256, 0, stream>>>(topi, offsets, cursors, perm, slotrow);

  if (fast) {
    transpose_kernel<<<dim3(1024, 16), 256, 0, stream>>>(w1, w2, w1t, w2t);
    // 1-D grid: p%8 = expert = XCD; GEMM1 mtile-fastest, GEMM2 ntile-fastest
    gemm_t_kernel<DMODEL, FFN, true, true, false>
        <<<NEXP * (FFN / 128) * 64, 256, 0, stream>>>(xb, w1t, H, offsets, perm);
    gemm_t_kernel<FFN, DMODEL, false, false, true>
        <<<NEXP * (DMODEL / 128) * 64, 256, 0, stream>>>(H, w2t, Y, offsets, perm);
  } else {
    gemm_f_kernel<DMODEL, FFN, true, true>
        <<<dim3(FFN / 128, 64, NEXP), 256, 0, stream>>>(xb, w1, H, offsets, perm);
    gemm_f_kernel<FFN, DMODEL, false, false>
        <<<dim3(DMODEL / 128, 64, NEXP), 256, 0, stream>>>(H, w2, Y, offsets, perm);
  }
  combine_kernel<<<(T_TOK * DMODEL / 4) / 256, 256, 0, stream>>>(Y, slotrow, topw, out);
}